// Round 17
// baseline (93.182 us; speedup 1.0000x reference)
//
#include <hip/hip_runtime.h>
#include <cstdint>

typedef unsigned short ushort_t;
typedef __attribute__((ext_vector_type(4))) float f32x4;
typedef __attribute__((ext_vector_type(8))) __bf16 bf16x8;
typedef __attribute__((ext_vector_type(8))) unsigned short ushort8;

#define NB 16384
#define DK 1024   // IN + H

#define MFMA16(a, b, c) __builtin_amdgcn_mfma_f32_16x16x32_bf16(a, b, c, 0, 0, 0)

__device__ __forceinline__ unsigned short f2b(float f) {
    unsigned u = __builtin_bit_cast(unsigned, f);
    unsigned r = u + 0x7fffu + ((u >> 16) & 1u);
    return (unsigned short)(r >> 16);
}
__device__ __forceinline__ float b2f(ushort_t b) {
    unsigned u = ((unsigned)b) << 16;
    return __builtin_bit_cast(float, u);
}
__device__ __forceinline__ float fast_sigmoid(float x) {
    return __fdividef(1.0f, 1.0f + __expf(-x));
}
__device__ __forceinline__ float fast_tanh(float x) {
    return __fdividef(2.0f, 1.0f + __expf(-2.0f * x)) - 1.0f;
}

__device__ __forceinline__ void gll16(const void* g, void* lds) {
    __builtin_amdgcn_global_load_lds(
        (__attribute__((address_space(1))) unsigned int*)(uintptr_t)g,
        (__attribute__((address_space(3))) unsigned int*)(unsigned int)(uintptr_t)lds,
        16, 0, 0);
}

// ---------------- prep kernels (proven; sources PRE-SWIZZLED) ----------------
// within each 64-elem K-group of a row, logical elem c stored at c ^ ((row&7)<<3).

__global__ __launch_bounds__(256) void k_cvt(const float* __restrict__ x,
                                             const float* __restrict__ h,
                                             ushort_t* __restrict__ XB,
                                             ushort_t* __restrict__ HB) {
    int b = blockIdx.x;
    const float* s;
    ushort_t* d;
    if (b < 4096) { s = x; d = XB; } else { s = h; d = HB; b -= 4096; }
    size_t g = (size_t)b * 256 + threadIdx.x;
    const float* p = s + g * 8;
    f32x4 f0 = *(const f32x4*)p;
    f32x4 f1 = *(const f32x4*)(p + 4);
    ushort8 o;
#pragma unroll
    for (int j = 0; j < 4; ++j) { o[j] = f2b(f0[j]); o[j + 4] = f2b(f1[j]); }
    size_t fi = g * 8;
    int row = (int)(fi >> 9);
    int c = (int)(fi & 511);  // multiple of 8
    int swc = (c & ~63) | ((c & 63) ^ ((row & 7) << 3));
    *(ushort8*)(d + (size_t)row * 512 + swc) = o;
}

__global__ __launch_bounds__(256) void k_transpose_w(const float* __restrict__ Wi,
                                                     const float* __restrict__ Wo,
                                                     ushort_t* __restrict__ WTI,
                                                     ushort_t* __restrict__ WTO) {
    const int z = blockIdx.z;
    if (z == 1 && blockIdx.x >= 16) return;
    const float* W = (z == 0) ? Wi : Wo;
    ushort_t* Wt = (z == 0) ? WTI : WTO;
    const int ncols = (z == 0) ? 1024 : 512;
    __shared__ float tile[32][33];
    int n0 = blockIdx.x * 32, k0 = blockIdx.y * 32;
    int tx = threadIdx.x & 31, ty = threadIdx.x >> 5;
#pragma unroll
    for (int i = 0; i < 32; i += 8)
        tile[ty + i][tx] = W[(size_t)(k0 + ty + i) * ncols + n0 + tx];
    __syncthreads();
#pragma unroll
    for (int i = 0; i < 32; i += 8) {
        int n = n0 + ty + i;
        int k = k0 + tx;
        int kk = (k & ~63) | ((k & 63) ^ ((n & 7) << 3));
        Wt[(size_t)n * DK + kk] = f2b(tile[tx][ty + i]);
    }
}

// ---------------- shared GEMM body (R11-proven 128x128 BK=64 2-phase) ----------------
// A2src: first 512 K from XB, rest from AH (HB or HN). WTbase points at the B panel
// rows for this kernel. Epilogue differs per kernel.

// k_gemmL: learn half. Writes raw accumulator (no bias) as bf16 LP, swizzled cols.
__global__ __launch_bounds__(256, 2) void k_gemmL(
    const ushort_t* __restrict__ XB, const ushort_t* __restrict__ AH,
    const ushort_t* __restrict__ WTbase, ushort_t* __restrict__ LP) {
    __shared__ ushort_t A2[2][128 * 64];
    __shared__ ushort_t B2[2][128 * 64];

    const int wg = blockIdx.x;                // 0..511, XCD-pinned
    const int xcd = wg & 7, q = wg >> 3;
    const int m0 = ((xcd << 4) | (q & 15)) * 128;
    const int n0 = (q >> 4) * 128;

    const int t = threadIdx.x;
    const int lane = t & 63;
    const int wave = t >> 6;
    const int wm = wave >> 1, wn = wave & 1;

    f32x4 acc[4][4] = {};

    const int srow = t >> 3;
    const int skel = (t & 7) * 8;
    const ushort_t* gB = WTbase + (size_t)(n0 + srow) * DK + skel;
    const int fr = lane & 15;
    const int fq = lane >> 4;
    const int xr = (fr & 7) << 3;

    auto stage = [&](int it, int buf) {
        const int kt = it * 64;
        const ushort_t* ab = (kt < 512)
            ? (XB + (size_t)(m0 + srow) * 512 + kt + skel)
            : (AH + (size_t)(m0 + srow) * 512 + (kt - 512) + skel);
        ushort_t* a = &A2[buf][t * 8];
        ushort_t* b = &B2[buf][t * 8];
#pragma unroll
        for (int r = 0; r < 4; ++r) {
            gll16(ab + (size_t)(32 * r) * 512, a + 2048 * r);
            gll16(gB + kt + (size_t)(32 * r) * DK, b + 2048 * r);
        }
    };

    stage(0, 0);
    for (int it = 0; it < 16; ++it) {
        asm volatile("s_waitcnt vmcnt(0)" ::: "memory");
        __syncthreads();
        if (it + 1 < 16) stage(it + 1, (it + 1) & 1);
        const int cur = it & 1;
#pragma unroll
        for (int kk = 0; kk < 2; ++kk) {
            bf16x8 av[4], bv[4];
#pragma unroll
            for (int i = 0; i < 4; ++i) {
                av[i] = *(const bf16x8*)(&A2[cur][(wm * 64 + i * 16 + fr) * 64 + ((kk * 32 + fq * 8) ^ xr)]);
                bv[i] = *(const bf16x8*)(&B2[cur][(wn * 64 + i * 16 + fr) * 64 + ((kk * 32 + fq * 8) ^ xr)]);
            }
            __builtin_amdgcn_s_setprio(1);
#pragma unroll
            for (int i = 0; i < 4; ++i)
#pragma unroll
                for (int j = 0; j < 4; ++j)
                    acc[i][j] = MFMA16(av[i], bv[j], acc[i][j]);
            __builtin_amdgcn_s_setprio(0);
        }
    }

#pragma unroll
    for (int i = 0; i < 4; ++i)
#pragma unroll
        for (int j = 0; j < 4; ++j) {
            const int c = n0 + wn * 64 + j * 16 + fr;
#pragma unroll
            for (int rr = 0; rr < 4; ++rr) {
                const int row = m0 + wm * 64 + i * 16 + fq * 4 + rr;
                const int sc = (c & ~63) | ((c & 63) ^ ((row & 7) << 3));
                LP[(size_t)row * 512 + sc] = f2b(acc[i][j][rr]);
            }
        }
}

// k_gemmF: forget half + full gate epilogue (reads LP + HB, writes hnew f32 + HN bf16).
__global__ __launch_bounds__(256, 2) void k_gemmF(
    const ushort_t* __restrict__ XB, const ushort_t* __restrict__ HB,
    const ushort_t* __restrict__ WTbase, const ushort_t* __restrict__ LP,
    const float* __restrict__ b_in, float* __restrict__ hnew,
    ushort_t* __restrict__ HN) {
    __shared__ ushort_t A2[2][128 * 64];
    __shared__ ushort_t B2[2][128 * 64];

    const int wg = blockIdx.x;
    const int xcd = wg & 7, q = wg >> 3;
    const int m0 = ((xcd << 4) | (q & 15)) * 128;
    const int n0 = (q >> 4) * 128;

    const int t = threadIdx.x;
    const int lane = t & 63;
    const int wave = t >> 6;
    const int wm = wave >> 1, wn = wave & 1;

    f32x4 acc[4][4] = {};

    const int srow = t >> 3;
    const int skel = (t & 7) * 8;
    const ushort_t* gB = WTbase + (size_t)(n0 + srow) * DK + skel;
    const int fr = lane & 15;
    const int fq = lane >> 4;
    const int xr = (fr & 7) << 3;

    auto stage = [&](int it, int buf) {
        const int kt = it * 64;
        const ushort_t* ab = (kt < 512)
            ? (XB + (size_t)(m0 + srow) * 512 + kt + skel)
            : (HB + (size_t)(m0 + srow) * 512 + (kt - 512) + skel);
        ushort_t* a = &A2[buf][t * 8];
        ushort_t* b = &B2[buf][t * 8];
#pragma unroll
        for (int r = 0; r < 4; ++r) {
            gll16(ab + (size_t)(32 * r) * 512, a + 2048 * r);
            gll16(gB + kt + (size_t)(32 * r) * DK, b + 2048 * r);
        }
    };

    stage(0, 0);
    for (int it = 0; it < 16; ++it) {
        asm volatile("s_waitcnt vmcnt(0)" ::: "memory");
        __syncthreads();
        if (it + 1 < 16) stage(it + 1, (it + 1) & 1);
        const int cur = it & 1;
#pragma unroll
        for (int kk = 0; kk < 2; ++kk) {
            bf16x8 av[4], bv[4];
#pragma unroll
            for (int i = 0; i < 4; ++i) {
                av[i] = *(const bf16x8*)(&A2[cur][(wm * 64 + i * 16 + fr) * 64 + ((kk * 32 + fq * 8) ^ xr)]);
                bv[i] = *(const bf16x8*)(&B2[cur][(wn * 64 + i * 16 + fr) * 64 + ((kk * 32 + fq * 8) ^ xr)]);
            }
            __builtin_amdgcn_s_setprio(1);
#pragma unroll
            for (int i = 0; i < 4; ++i)
#pragma unroll
                for (int j = 0; j < 4; ++j)
                    acc[i][j] = MFMA16(av[i], bv[j], acc[i][j]);
            __builtin_amdgcn_s_setprio(0);
        }
    }

    // gate epilogue: fp = acc + b_in[c+512]; lp = LP + b_in[c]; hv = HB
#pragma unroll
    for (int i = 0; i < 4; ++i)
#pragma unroll
        for (int j = 0; j < 4; ++j) {
            const int c = n0 + wn * 64 + j * 16 + fr;
            const float bl = b_in[c];
            const float bf = b_in[c + 512];
#pragma unroll
            for (int rr = 0; rr < 4; ++rr) {
                const int row = m0 + wm * 64 + i * 16 + fq * 4 + rr;
                const int sc = (c & ~63) | ((c & 63) ^ ((row & 7) << 3));
                float lp = b2f(LP[(size_t)row * 512 + sc]) + bl;
                float fp = acc[i][j][rr] + bf;
                float hv = b2f(HB[(size_t)row * 512 + sc]);
                float fm = fast_sigmoid(fp);
                float lr = fast_tanh(lp);
                float hn = lr + fm * (hv - lr);
                hnew[(size_t)row * 512 + c] = hn;
                HN[(size_t)row * 512 + sc] = f2b(hn);
            }
        }
}

// k_gemm2: out = tanh([x,h_new] @ W_out + b_out)  (R11-proven form)
__global__ __launch_bounds__(256, 2) void k_gemm2(
    const ushort_t* __restrict__ XB, const ushort_t* __restrict__ HN,
    const ushort_t* __restrict__ WT, const float* __restrict__ b_out,
    float* __restrict__ out) {
    __shared__ ushort_t A2[2][128 * 64];
    __shared__ ushort_t B2[2][128 * 64];

    const int wg = blockIdx.x;
    const int xcd = wg & 7, q = wg >> 3;
    const int m0 = ((xcd << 4) | (q & 15)) * 128;
    const int n0 = (q >> 4) * 128;

    const int t = threadIdx.x;
    const int lane = t & 63;
    const int wave = t >> 6;
    const int wm = wave >> 1, wn = wave & 1;

    f32x4 acc[4][4] = {};

    const int srow = t >> 3;
    const int skel = (t & 7) * 8;
    const ushort_t* gB = WT + (size_t)(n0 + srow) * DK + skel;
    const int fr = lane & 15;
    const int fq = lane >> 4;
    const int xr = (fr & 7) << 3;

    auto stage = [&](int it, int buf) {
        const int kt = it * 64;
        const ushort_t* ab = (kt < 512)
            ? (XB + (size_t)(m0 + srow) * 512 + kt + skel)
            : (HN + (size_t)(m0 + srow) * 512 + (kt - 512) + skel);
        ushort_t* a = &A2[buf][t * 8];
        ushort_t* b = &B2[buf][t * 8];
#pragma unroll
        for (int r = 0; r < 4; ++r) {
            gll16(ab + (size_t)(32 * r) * 512, a + 2048 * r);
            gll16(gB + kt + (size_t)(32 * r) * DK, b + 2048 * r);
        }
    };

    stage(0, 0);
    for (int it = 0; it < 16; ++it) {
        asm volatile("s_waitcnt vmcnt(0)" ::: "memory");
        __syncthreads();
        if (it + 1 < 16) stage(it + 1, (it + 1) & 1);
        const int cur = it & 1;
#pragma unroll
        for (int kk = 0; kk < 2; ++kk) {
            bf16x8 av[4], bv[4];
#pragma unroll
            for (int i = 0; i < 4; ++i) {
                av[i] = *(const bf16x8*)(&A2[cur][(wm * 64 + i * 16 + fr) * 64 + ((kk * 32 + fq * 8) ^ xr)]);
                bv[i] = *(const bf16x8*)(&B2[cur][(wn * 64 + i * 16 + fr) * 64 + ((kk * 32 + fq * 8) ^ xr)]);
            }
            __builtin_amdgcn_s_setprio(1);
#pragma unroll
            for (int i = 0; i < 4; ++i)
#pragma unroll
                for (int j = 0; j < 4; ++j)
                    acc[i][j] = MFMA16(av[i], bv[j], acc[i][j]);
            __builtin_amdgcn_s_setprio(0);
        }
    }

#pragma unroll
    for (int i = 0; i < 4; ++i)
#pragma unroll
        for (int j = 0; j < 4; ++j) {
            const int c = n0 + wn * 64 + j * 16 + fr;
            const float bo = b_out[c];
#pragma unroll
            for (int rr = 0; rr < 4; ++rr) {
                const int row = m0 + wm * 64 + i * 16 + fq * 4 + rr;
                out[(size_t)row * 512 + c] = fast_tanh(acc[i][j][rr] + bo);
            }
        }
}

extern "C" void kernel_launch(void* const* d_in, const int* in_sizes, int n_in,
                              void* d_out, int out_size, void* d_ws, size_t ws_size,
                              hipStream_t stream) {
    const float* x = (const float*)d_in[0];
    const float* h = (const float*)d_in[1];
    const float* W_in = (const float*)d_in[2];
    const float* b_in = (const float*)d_in[3];
    const float* W_out = (const float*)d_in[4];
    const float* b_out = (const float*)d_in[5];

    float* out = (float*)d_out;                    // [16384][512]
    float* hnew = out + (size_t)NB * 512;          // [16384][512]

    // workspace: XB,HB,HN,LP bf16 16MB each + WTI 2MB + WTO 1MB = 67MB
    ushort_t* XB = (ushort_t*)d_ws;
    ushort_t* HB = XB + (size_t)NB * 512;
    ushort_t* HN = HB + (size_t)NB * 512;
    ushort_t* LP = HN + (size_t)NB * 512;
    ushort_t* WTI = LP + (size_t)NB * 512;
    ushort_t* WTO = WTI + (size_t)1024 * 1024;

    k_cvt<<<8192, 256, 0, stream>>>(x, h, XB, HB);
    k_transpose_w<<<dim3(32, 32, 2), 256, 0, stream>>>(W_in, W_out, WTI, WTO);
    k_gemmL<<<512, 256, 0, stream>>>(XB, HB, WTI, LP);
    k_gemmF<<<512, 256, 0, stream>>>(XB, HB, WTI + (size_t)512 * DK, LP, b_in, hnew, HN);
    k_gemm2<<<512, 256, 0, stream>>>(XB, HN, WTO, b_out, out);
}